// Round 14
// baseline (284.179 us; speedup 1.0000x reference)
//
#include <hip/hip_runtime.h>

#define S_LEN    2048
#define D_MODEL  1024
#define N_HEADS  16
#define HEAD_DIM 64
#define BATCH    2

typedef __bf16 bf16x8 __attribute__((ext_vector_type(8)));
typedef float  floatx4 __attribute__((ext_vector_type(4)));

__device__ __forceinline__ unsigned short f2bf(float f) {
    union { float f; unsigned int u; } v;
    v.f = f;
    unsigned int u = v.u;
    u += 0x7fffu + ((u >> 16) & 1u);   // RNE
    return (unsigned short)(u >> 16);
}

// pack two floats to bf16 pair (a -> low, b -> high), RNE
__device__ __forceinline__ unsigned int pk_rne(float a, float b) {
    union { float f; unsigned int u; } ua, ub;
    ua.f = a; ub.f = b;
    unsigned int x = ua.u + 0x7fffu + ((ua.u >> 16) & 1u);
    unsigned int y = ub.u + 0x7fffu + ((ub.u >> 16) & 1u);
    return __builtin_amdgcn_perm(y, x, 0x07060302);  // low = x.hi16, high = y.hi16
}

__device__ __forceinline__ void gload_lds16(const unsigned short* g, unsigned short* l) {
    __builtin_amdgcn_global_load_lds(
        (const __attribute__((address_space(1))) void*)(const void*)g,
        (__attribute__((address_space(3))) void*)(void*)l,
        16, 0, 0);
}

// ---------- prep: W[K][N] -> Wt[N][K] bf16 (weights only; activation conversion
// is fused into qkv_gemm A-staging, bit-identical RNE) ----------
struct PrepArgs {
    const float* W[4];   unsigned short* Wt[4];
};

__global__ void prep_kernel(PrepArgs args) {
    __shared__ unsigned short tile[64][65];
    const int r  = blockIdx.x;           // 0..1023
    const int w  = r >> 8;               // weight 0..3
    const int xy = r & 255;
    const int n0 = (xy & 15) * 64, k0 = (xy >> 4) * 64;
    const float* W = args.W[w];
    unsigned short* Wt = args.Wt[w];
    for (int rep = 0; rep < 16; ++rep) {
        int e = rep * 256 + threadIdx.x;
        int kk = e >> 6, nn = e & 63;
        tile[kk][nn] = f2bf(W[(size_t)(k0 + kk) * D_MODEL + n0 + nn]);
    }
    __syncthreads();
    for (int rep = 0; rep < 16; ++rep) {
        int e = rep * 256 + threadIdx.x;
        int nn = e >> 6, kk = e & 63;
        Wt[(size_t)(n0 + nn) * D_MODEL + k0 + kk] = tile[kk][nn];
    }
}

// ---------- GEMM core: C[TM][TN] tile of A[M][1024] * Bt[N][1024]^T + bias ----------
// 2-PHASE DOUBLE-BUFFERED K-loop (T3 minimum recipe): each iteration issues the
// NEXT K-tile's loads (A reg-loads for AF32 / gload_lds, B gload_lds) BEFORE
// computing the current tile, with ONE barrier at iteration end. The prefetch
// gets the whole compute phase of flight (~400-500 cyc) instead of 0 (old
// structure barrier'd immediately after issue). AF32's cvt+ds_write runs AFTER
// compute so the reg-load latency hides under MFMA (T14 split).
// BK=64, attn-proven conflict-free LDS layout (R10). Bit-identical math.
// MODE 0: bf16 out, [B,H,S,DK];  MODE 1: bf16 out, [B,H,DK,S];  MODE 2: fp32 [M][N]
template <int TM, int TN, int MODE, bool AF32>
__device__ __forceinline__
void gemm_body(const void* __restrict__ A,
               const unsigned short* __restrict__ Bt,
               const float* __restrict__ bias,
               void* __restrict__ out,
               int m0, int n0, float scale,
               unsigned short* As0, unsigned short* Bs0) {
    constexpr int MT   = TM / 32;
    constexpr int NT   = TN / 32;
    constexpr int ABUF = TM * 64;      // shorts per A buffer
    constexpr int BBUF = TN * 64;
    constexpr int NIT  = D_MODEL / 64; // 16 K-iterations
    const int tid  = threadIdx.x;
    const int wid  = tid >> 6;
    const int lane = tid & 63;

    floatx4 acc[MT][NT];
#pragma unroll
    for (int i = 0; i < MT; ++i)
#pragma unroll
        for (int j = 0; j < NT; ++j) acc[i][j] = (floatx4)0.0f;

    const int srow = lane >> 3;            // 0..7 within 8-row chunk
    const int gch  = (lane & 7) ^ srow;    // swizzled 16B granule within row
    const int wr = (wid >> 1) * (TM / 2);
    const int wc = (wid & 1) * (TN / 2);
    const int fr = lane & 15;
    const int fq = lane >> 4;
    const int sw7 = fr & 7;

    // ---- prologue: stage K-tile 0 into buffer 0 ----
    if constexpr (AF32) {
#pragma unroll
        for (int ci = 0; ci < MT; ++ci) {
            const int c = wid + ci * 4;
            const float* src = (const float*)A + (size_t)(m0 + c * 8 + srow) * D_MODEL + gch * 8;
            float4 f0 = reinterpret_cast<const float4*>(src)[0];
            float4 f1 = reinterpret_cast<const float4*>(src)[1];
            uint4 wv;
            wv.x = pk_rne(f0.x, f0.y); wv.y = pk_rne(f0.z, f0.w);
            wv.z = pk_rne(f1.x, f1.y); wv.w = pk_rne(f1.z, f1.w);
            *reinterpret_cast<uint4*>(As0 + c * 512 + lane * 8) = wv;
        }
    } else {
#pragma unroll
        for (int ci = 0; ci < MT; ++ci) {
            const int c = wid + ci * 4;
            gload_lds16((const unsigned short*)A + (size_t)(m0 + c * 8 + srow) * D_MODEL + gch * 8,
                        As0 + c * 512);
        }
    }
#pragma unroll
    for (int ci = 0; ci < NT; ++ci) {
        const int cb = wid + ci * 4;
        gload_lds16(Bt + (size_t)(n0 + cb * 8 + srow) * D_MODEL + gch * 8, Bs0 + cb * 512);
    }
    __syncthreads();

    for (int it = 0; it < NIT; ++it) {
        const int cur = it & 1;
        unsigned short* Ac = As0 + cur * ABUF;
        unsigned short* Bc = Bs0 + cur * BBUF;
        unsigned short* An = As0 + (cur ^ 1) * ABUF;
        unsigned short* Bn = Bs0 + (cur ^ 1) * BBUF;
        const int kn = (it + 1) * 64;
        const bool pf = (it + 1 < NIT);   // block-uniform

        // ---- issue next tile's loads (flight covered by compute below) ----
        float4 fa[MT][2];
        if (pf) {
            if constexpr (AF32) {
#pragma unroll
                for (int ci = 0; ci < MT; ++ci) {
                    const int c = wid + ci * 4;
                    const float* src = (const float*)A + (size_t)(m0 + c * 8 + srow) * D_MODEL + kn + gch * 8;
                    fa[ci][0] = reinterpret_cast<const float4*>(src)[0];
                    fa[ci][1] = reinterpret_cast<const float4*>(src)[1];
                }
            } else {
#pragma unroll
                for (int ci = 0; ci < MT; ++ci) {
                    const int c = wid + ci * 4;
                    gload_lds16((const unsigned short*)A + (size_t)(m0 + c * 8 + srow) * D_MODEL + kn + gch * 8,
                                An + c * 512);
                }
            }
#pragma unroll
            for (int ci = 0; ci < NT; ++ci) {
                const int cb = wid + ci * 4;
                gload_lds16(Bt + (size_t)(n0 + cb * 8 + srow) * D_MODEL + kn + gch * 8, Bn + cb * 512);
            }
        }

        // ---- compute current tile ----
#pragma unroll
        for (int kk = 0; kk < 2; ++kk) {
            bf16x8 af[MT], bfv[NT];
#pragma unroll
            for (int t = 0; t < MT; ++t)
                af[t] = *reinterpret_cast<const bf16x8*>(
                    Ac + (wr + t * 16 + fr) * 64 + (((kk * 4 + fq) ^ sw7) * 8));
#pragma unroll
            for (int t = 0; t < NT; ++t)
                bfv[t] = *reinterpret_cast<const bf16x8*>(
                    Bc + (wc + t * 16 + fr) * 64 + (((kk * 4 + fq) ^ sw7) * 8));
#pragma unroll
            for (int mt = 0; mt < MT; ++mt)
#pragma unroll
                for (int nt = 0; nt < NT; ++nt)
                    acc[mt][nt] = __builtin_amdgcn_mfma_f32_16x16x32_bf16(af[mt], bfv[nt], acc[mt][nt], 0, 0, 0);
        }

        // ---- AF32: convert + write next A tile (reg-loads landed during compute) ----
        if (pf) {
            if constexpr (AF32) {
#pragma unroll
                for (int ci = 0; ci < MT; ++ci) {
                    const int c = wid + ci * 4;
                    uint4 wv;
                    wv.x = pk_rne(fa[ci][0].x, fa[ci][0].y); wv.y = pk_rne(fa[ci][0].z, fa[ci][0].w);
                    wv.z = pk_rne(fa[ci][1].x, fa[ci][1].y); wv.w = pk_rne(fa[ci][1].z, fa[ci][1].w);
                    *reinterpret_cast<uint4*>(An + c * 512 + lane * 8) = wv;
                }
            }
            __syncthreads();   // next tile ready; all waves done reading cur
        }
    }

#pragma unroll
    for (int nt = 0; nt < NT; ++nt) {
        const int n = n0 + wc + nt * 16 + fr;
        const float bval = bias[n];
#pragma unroll
        for (int mt = 0; mt < MT; ++mt) {
#pragma unroll
            for (int r = 0; r < 4; ++r) {
                const int m = m0 + wr + mt * 16 + fq * 4 + r;
                const float val = (acc[mt][nt][r] + bval) * scale;
                if (MODE == 2) {
                    reinterpret_cast<float*>(out)[(size_t)m * D_MODEL + n] = val;
                } else {
                    const int b = m >> 11, s = m & (S_LEN - 1);
                    const int h = n >> 6, dk = n & 63;
                    const unsigned short o16 = f2bf(val);
                    if (MODE == 0)
                        reinterpret_cast<unsigned short*>(out)[(((size_t)(b * N_HEADS + h)) * S_LEN + s) * HEAD_DIM + dk] = o16;
                    else
                        reinterpret_cast<unsigned short*>(out)[(((size_t)(b * N_HEADS + h)) * HEAD_DIM + dk) * S_LEN + s] = o16;
                }
            }
        }
    }
}

// fused Q/K/V projection (A = original fp32 activations; conversion fused in staging)
struct QKVArgs {
    const float* A[3];
    const unsigned short* Bt[3];
    const float* bias[3];
    unsigned short* out[3];
};

// XCD-chunked swizzle (R9): per z-slice, 256 tiles; XCD k gets tiles k*32..k*32+31
// = 4 m-panels x 8 n-panels -> per-XCD L2 working set 2 MB A(fp32) + 2 MB B;
// each A panel fetched by exactly one XCD. LDS 64 KB (double-buffered) -> 2
// blocks/CU; the prefetch replaces the lost cross-block latency cover.
__global__ __launch_bounds__(256)
void qkv_gemm_kernel(QKVArgs args) {
    __shared__ __align__(16) unsigned short smem[4 * 128 * 64];  // 64 KB: A0 A1 B0 B1
    unsigned short* As0 = smem;
    unsigned short* Bs0 = smem + 2 * 128 * 64;
    const int z  = blockIdx.z;
    const int wg = blockIdx.x + (blockIdx.y << 3);     // 0..255 linear within slice
    const int t  = ((wg & 7) << 5) + (wg >> 3);        // bijective (256 % 8 == 0)
    const int n0 = (t & 7) * 128;
    const int m0 = (t >> 3) * 128;
    // Q gets 0.125*log2(e) folded in so attention uses exp2 with no per-element scale
    if (z == 0)
        gemm_body<128, 128, 0, true>(args.A[0], args.Bt[0], args.bias[0], args.out[0], m0, n0, 0.18033688011112f, As0, Bs0);
    else if (z == 1)
        gemm_body<128, 128, 0, true>(args.A[1], args.Bt[1], args.bias[1], args.out[1], m0, n0, 1.0f, As0, Bs0);
    else
        gemm_body<128, 128, 1, true>(args.A[2], args.Bt[2], args.bias[2], args.out[2], m0, n0, 1.0f, As0, Bs0);
}

// O projection: 64x128 tiles -> 512 blocks, same XCD-chunked swizzle; 48 KB LDS.
__global__ __launch_bounds__(256)
void oproj_gemm_kernel(const unsigned short* __restrict__ A,
                       const unsigned short* __restrict__ Bt,
                       const float* __restrict__ bias,
                       float* __restrict__ out) {
    __shared__ __align__(16) unsigned short smem[2 * 64 * 64 + 2 * 128 * 64];  // 48 KB
    unsigned short* As0 = smem;
    unsigned short* Bs0 = smem + 2 * 64 * 64;
    const int wg = blockIdx.x + (blockIdx.y << 3);     // 0..511
    const int t  = ((wg & 7) << 6) + (wg >> 3);        // bijective (512 % 8 == 0)
    const int n0 = (t & 7) * 128;
    const int m0 = (t >> 3) * 64;
    gemm_body<64, 128, 2, false>(A, Bt, bias, out, m0, n0, 1.0f, As0, Bs0);
}

// ---------- attention (R0 verbatim — best measured structure) ----------
// 128 threads (2 waves), 64 q rows/block, 32 q rows/wave (2 subtiles of 16).
// Grid 1024 blocks -> 4 blocks/CU (LDS 33 KB) = 4 independent barrier domains/CU,
// so one block's global_load_lds drain overlaps another's MFMA/VALU compute.
// S^T = K Q^T so per-lane acc is contiguous kv; P packs via pk_rne -> b64 write.
__global__ __launch_bounds__(128)
void attn_kernel(const unsigned short* __restrict__ qhp,
                 const unsigned short* __restrict__ khp,
                 const unsigned short* __restrict__ vtp,
                 unsigned short* __restrict__ outp) {
    __shared__ __align__(16) unsigned short Qs[64 * 64];
    __shared__ __align__(16) unsigned short Ks[64 * 64];
    __shared__ __align__(16) unsigned short Vs[64 * 64];
    __shared__ __align__(16) unsigned short Ps[2][32 * 72];  // per-wave [q_local][kv]

    const int tid  = threadIdx.x;
    const int wid  = tid >> 6;             // 0..1
    const int lane = tid & 63;
    const int b = blockIdx.z, h = blockIdx.y;
    const int q0 = blockIdx.x * 64;

    const unsigned short* qbase = qhp + (size_t)(b * N_HEADS + h) * S_LEN * HEAD_DIM;
    const unsigned short* kbase = khp + (size_t)(b * N_HEADS + h) * S_LEN * HEAD_DIM;
    const unsigned short* vbase = vtp + (size_t)(b * N_HEADS + h) * HEAD_DIM * S_LEN;

    const int srow = lane >> 3;            // 0..7
    const int gch  = (lane & 7) ^ srow;    // swizzled 16B chunk within 128B row
    const int fr = lane & 15;
    const int fq = lane >> 4;
    const int sw7 = fr & 7;

    // stage Q (64 rows = 8 chunks of 8 rows); wave wid takes chunks wid*4..wid*4+3
#pragma unroll
    for (int i = 0; i < 4; ++i) {
        const int c = wid * 4 + i;
        const int row = c * 8 + srow;
        gload_lds16(qbase + (size_t)(q0 + row) * HEAD_DIM + gch * 8, Qs + c * 512);
    }
    __syncthreads();

    // hoist Q B-operand fragments: subtile qh2 covers rows wid*32 + qh2*16 + fr
    bf16x8 qf[2][2];
#pragma unroll
    for (int qh2 = 0; qh2 < 2; ++qh2)
#pragma unroll
        for (int kk = 0; kk < 2; ++kk)
            qf[qh2][kk] = *reinterpret_cast<const bf16x8*>(
                Qs + (wid * 32 + qh2 * 16 + fr) * 64 + (((kk * 4 + fq) ^ sw7) * 8));

    floatx4 o_acc[2][4];
#pragma unroll
    for (int i = 0; i < 2; ++i)
#pragma unroll
        for (int j = 0; j < 4; ++j) o_acc[i][j] = (floatx4)0.0f;
    float l_sum[2] = {0.0f, 0.0f};

    for (int kv0 = 0; kv0 < S_LEN; kv0 += 64) {
        if (kv0) __syncthreads();
#pragma unroll
        for (int i = 0; i < 4; ++i) {
            const int c = wid * 4 + i;
            const int row = c * 8 + srow;
            gload_lds16(kbase + (size_t)(kv0 + row) * HEAD_DIM + gch * 8, Ks + c * 512);
            gload_lds16(vbase + (size_t)row * S_LEN + kv0 + gch * 8,       Vs + c * 512);
        }
        __syncthreads();

        // S^T[kv][q]: A = K rows (shared across q subtiles), B = Q rows
        floatx4 st[2][4];
#pragma unroll
        for (int i = 0; i < 2; ++i)
#pragma unroll
            for (int j = 0; j < 4; ++j) st[i][j] = (floatx4)0.0f;
#pragma unroll
        for (int nt = 0; nt < 4; ++nt) {
#pragma unroll
            for (int kk = 0; kk < 2; ++kk) {
                bf16x8 kf = *reinterpret_cast<const bf16x8*>(
                    Ks + (nt * 16 + fr) * 64 + (((kk * 4 + fq) ^ sw7) * 8));
                st[0][nt] = __builtin_amdgcn_mfma_f32_16x16x32_bf16(kf, qf[0][kk], st[0][nt], 0, 0, 0);
                st[1][nt] = __builtin_amdgcn_mfma_f32_16x16x32_bf16(kf, qf[1][kk], st[1][nt], 0, 0, 0);
            }
        }

        // P = exp2(S^T) (scale pre-folded into Q); lane holds P[q=fr][kv=nt*16+fq*4+r]
#pragma unroll
        for (int qh2 = 0; qh2 < 2; ++qh2) {
#pragma unroll
            for (int nt = 0; nt < 4; ++nt) {
                float p0 = __builtin_amdgcn_exp2f(st[qh2][nt][0]);
                float p1 = __builtin_amdgcn_exp2f(st[qh2][nt][1]);
                float p2 = __builtin_amdgcn_exp2f(st[qh2][nt][2]);
                float p3 = __builtin_amdgcn_exp2f(st[qh2][nt][3]);
                l_sum[qh2] += (p0 + p1) + (p2 + p3);
                uint2 w;
                w.x = pk_rne(p0, p1);
                w.y = pk_rne(p2, p3);
                *reinterpret_cast<uint2*>(Ps[wid] + (qh2 * 16 + fr) * 72 + nt * 16 + fq * 4) = w;
            }
        }
        __asm__ volatile("s_waitcnt lgkmcnt(0)" ::: "memory");  // wave-local write->read fence

        // O += P V   (Vs = V^T rows [d][kv]; V fragments shared across q subtiles)
#pragma unroll
        for (int kk = 0; kk < 2; ++kk) {
            bf16x8 pf0 = *reinterpret_cast<const bf16x8*>(Ps[wid] + (fr)      * 72 + kk * 32 + fq * 8);
            bf16x8 pf1 = *reinterpret_cast<const bf16x8*>(Ps[wid] + (16 + fr) * 72 + kk * 32 + fq * 8);
#pragma unroll
            for (int dt = 0; dt < 4; ++dt) {
                bf16x8 vf = *reinterpret_cast<const bf16x8*>(
                    Vs + (dt * 16 + fr) * 64 + (((kk * 4 + fq) ^ sw7) * 8));
                o_acc[0][dt] = __builtin_amdgcn_mfma_f32_16x16x32_bf16(pf0, vf, o_acc[0][dt], 0, 0, 0);
                o_acc[1][dt] = __builtin_amdgcn_mfma_f32_16x16x32_bf16(pf1, vf, o_acc[1][dt], 0, 0, 0);
            }
        }
    }

#pragma unroll
    for (int qh2 = 0; qh2 < 2; ++qh2) {
        float l = l_sum[qh2];
        l += __shfl_xor(l, 16);
        l += __shfl_xor(l, 32);
        float linv[4];
#pragma unroll
        for (int r = 0; r < 4; ++r)
            linv[r] = __builtin_amdgcn_rcpf(__shfl(l, fq * 4 + r));
#pragma unroll
        for (int dt = 0; dt < 4; ++dt) {
#pragma unroll
            for (int r = 0; r < 4; ++r) {
                const int s  = q0 + wid * 32 + qh2 * 16 + fq * 4 + r;
                const int dk = dt * 16 + fr;
                const float val = o_acc[qh2][dt][r] * linv[r];
                outp[((size_t)(b * S_LEN + s)) * D_MODEL + h * HEAD_DIM + dk] = f2bf(val);
            }
        }
    }
}

extern "C" void kernel_launch(void* const* d_in, const int* in_sizes, int n_in,
                              void* d_out, int out_size, void* d_ws, size_t ws_size,
                              hipStream_t stream) {
    (void)in_sizes; (void)n_in; (void)out_size; (void)ws_size;
    const float* q  = (const float*)d_in[0];
    const float* k  = (const float*)d_in[1];
    const float* v  = (const float*)d_in[2];
    // d_in[3] = mask: mathematical no-op in the reference
    const float* Wq = (const float*)d_in[4];
    const float* bq = (const float*)d_in[5];
    const float* Wk = (const float*)d_in[6];
    const float* bk = (const float*)d_in[7];
    const float* Wv = (const float*)d_in[8];
    const float* bv = (const float*)d_in[9];
    const float* Wo = (const float*)d_in[10];
    const float* bo = (const float*)d_in[11];
    float* out = (float*)d_out;

    char* ws = (char*)d_ws;
    const size_t SZ_ACT = (size_t)BATCH * S_LEN * D_MODEL * 2;  // 8 MB
    const size_t SZ_W   = (size_t)D_MODEL * D_MODEL * 2;        // 2 MB
    unsigned short* attn = (unsigned short*)(ws);               // bf16 attn output
    unsigned short* Wqt  = (unsigned short*)(ws + 3 * SZ_ACT);
    unsigned short* Wkt  = (unsigned short*)(ws + 3 * SZ_ACT + SZ_W);
    unsigned short* Wvt  = (unsigned short*)(ws + 3 * SZ_ACT + 2 * SZ_W);
    unsigned short* Wot  = (unsigned short*)(ws + 3 * SZ_ACT + 3 * SZ_W);
    unsigned short* qhb  = (unsigned short*)(ws + 3 * SZ_ACT + 4 * SZ_W);
    unsigned short* khb  = (unsigned short*)(ws + 4 * SZ_ACT + 4 * SZ_W);
    unsigned short* vtb  = (unsigned short*)(ws + 5 * SZ_ACT + 4 * SZ_W);

    PrepArgs pargs;
    pargs.W[0] = Wq;  pargs.W[1] = Wk;  pargs.W[2] = Wv;  pargs.W[3] = Wo;
    pargs.Wt[0] = Wqt; pargs.Wt[1] = Wkt; pargs.Wt[2] = Wvt; pargs.Wt[3] = Wot;
    prep_kernel<<<dim3(1024), 256, 0, stream>>>(pargs);

    QKVArgs gargs;
    gargs.A[0] = q;  gargs.A[1] = k;  gargs.A[2] = v;
    gargs.Bt[0] = Wqt; gargs.Bt[1] = Wkt; gargs.Bt[2] = Wvt;
    gargs.bias[0] = bq; gargs.bias[1] = bk; gargs.bias[2] = bv;
    gargs.out[0] = qhb; gargs.out[1] = khb; gargs.out[2] = vtb;
    qkv_gemm_kernel<<<dim3(8, 32, 3), 256, 0, stream>>>(gargs);

    attn_kernel<<<dim3(S_LEN / 64, N_HEADS, BATCH), 128, 0, stream>>>(qhb, khb, vtb, attn);

    oproj_gemm_kernel<<<dim3(8, 64), 256, 0, stream>>>(attn, Wot, bo, out);
}

// Round 15
// 247.516 us; speedup vs baseline: 1.1481x; 1.1481x over previous
//
#include <hip/hip_runtime.h>

#define S_LEN    2048
#define D_MODEL  1024
#define N_HEADS  16
#define HEAD_DIM 64
#define BATCH    2

typedef __bf16 bf16x8 __attribute__((ext_vector_type(8)));
typedef float  floatx4 __attribute__((ext_vector_type(4)));

__device__ __forceinline__ unsigned short f2bf(float f) {
    union { float f; unsigned int u; } v;
    v.f = f;
    unsigned int u = v.u;
    u += 0x7fffu + ((u >> 16) & 1u);   // RNE
    return (unsigned short)(u >> 16);
}

// pack two floats to bf16 pair (a -> low, b -> high), RNE
__device__ __forceinline__ unsigned int pk_rne(float a, float b) {
    union { float f; unsigned int u; } ua, ub;
    ua.f = a; ub.f = b;
    unsigned int x = ua.u + 0x7fffu + ((ua.u >> 16) & 1u);
    unsigned int y = ub.u + 0x7fffu + ((ub.u >> 16) & 1u);
    return __builtin_amdgcn_perm(y, x, 0x07060302);  // low = x.hi16, high = y.hi16
}

__device__ __forceinline__ void gload_lds16(const unsigned short* g, unsigned short* l) {
    __builtin_amdgcn_global_load_lds(
        (const __attribute__((address_space(1))) void*)(const void*)g,
        (__attribute__((address_space(3))) void*)(void*)l,
        16, 0, 0);
}

// ---------- fused prep: fp32->bf16 for q,k,v  +  W[K][N] -> Wt[N][K] bf16 ----------
struct PrepArgs {
    const float* src[3]; unsigned short* dst[3];
    const float* W[4];   unsigned short* Wt[4];
};

#define CONV_BLOCKS (3 * 4096)

__global__ void prep_kernel(PrepArgs args) {
    const int bid = blockIdx.x;
    if (bid < CONV_BLOCKS) {
        const int t   = bid >> 12;           // tensor 0..2
        const int blk = bid & 4095;
        const int i   = blk * 256 + threadIdx.x;
        float4 f = reinterpret_cast<const float4*>(args.src[t])[i];
        ushort4 o;
        o.x = f2bf(f.x); o.y = f2bf(f.y); o.z = f2bf(f.z); o.w = f2bf(f.w);
        reinterpret_cast<ushort4*>(args.dst[t])[i] = o;
    } else {
        __shared__ unsigned short tile[64][65];
        const int r  = bid - CONV_BLOCKS;    // 0..1023
        const int w  = r >> 8;               // weight 0..3
        const int xy = r & 255;
        const int n0 = (xy & 15) * 64, k0 = (xy >> 4) * 64;
        const float* W = args.W[w];
        unsigned short* Wt = args.Wt[w];
        for (int rep = 0; rep < 16; ++rep) {
            int e = rep * 256 + threadIdx.x;
            int kk = e >> 6, nn = e & 63;
            tile[kk][nn] = f2bf(W[(size_t)(k0 + kk) * D_MODEL + n0 + nn]);
        }
        __syncthreads();
        for (int rep = 0; rep < 16; ++rep) {
            int e = rep * 256 + threadIdx.x;
            int nn = e >> 6, kk = e & 63;
            Wt[(size_t)(n0 + nn) * D_MODEL + k0 + kk] = tile[kk][nn];
        }
    }
}

// ---------- GEMM core: C[TM][TN] tile of A[M][1024] * Bt[N][1024]^T + bias ----------
// BK=64: half the barrier/vmcnt drains of the BK=32 schedule at equal load and
// ds_read totals. Tile layout/staging/read pattern transplanted from attn_kernel
// (8-row chunks, gch=(lane&7)^srow staging, read granule ((kk*4+fq)^(fr&7)) in
// 64-col rows) — measured 0 bank conflicts (R10).
// MODE 0: bf16 out, [B,H,S,DK];  MODE 1: bf16 out, [B,H,DK,S];  MODE 2: fp32 [M][N]
template <int TM, int TN, int MODE>
__device__ __forceinline__
void gemm_body(const unsigned short* __restrict__ A,
               const unsigned short* __restrict__ Bt,
               const float* __restrict__ bias,
               void* __restrict__ out,
               int m0, int n0, float scale,
               unsigned short* As, unsigned short* Bs) {
    constexpr int MT = TM / 32;
    constexpr int NT = TN / 32;
    const int tid  = threadIdx.x;
    const int wid  = tid >> 6;
    const int lane = tid & 63;

    floatx4 acc[MT][NT];
#pragma unroll
    for (int i = 0; i < MT; ++i)
#pragma unroll
        for (int j = 0; j < NT; ++j) acc[i][j] = (floatx4)0.0f;

    const int srow = lane >> 3;            // 0..7 within 8-row chunk
    const int gch  = (lane & 7) ^ srow;    // swizzled 16B granule within 128B row
    const int wr = (wid >> 1) * (TM / 2);
    const int wc = (wid & 1) * (TN / 2);
    const int fr = lane & 15;
    const int fq = lane >> 4;
    const int sw7 = fr & 7;

    for (int k0 = 0; k0 < D_MODEL; k0 += 64) {
        if (k0) __syncthreads();
#pragma unroll
        for (int ci = 0; ci < (TM + TN) / 32; ++ci) {
            const int c = wid + ci * 4;
            if (c < TM / 8) {
                const int row = c * 8 + srow;
                gload_lds16(A + (size_t)(m0 + row) * D_MODEL + k0 + gch * 8, As + c * 512);
            } else {
                const int cb = c - TM / 8;
                const int row = cb * 8 + srow;
                gload_lds16(Bt + (size_t)(n0 + row) * D_MODEL + k0 + gch * 8, Bs + cb * 512);
            }
        }
        __syncthreads();

#pragma unroll
        for (int kk = 0; kk < 2; ++kk) {
            bf16x8 af[MT], bfv[NT];
#pragma unroll
            for (int t = 0; t < MT; ++t)
                af[t] = *reinterpret_cast<const bf16x8*>(
                    As + (wr + t * 16 + fr) * 64 + (((kk * 4 + fq) ^ sw7) * 8));
#pragma unroll
            for (int t = 0; t < NT; ++t)
                bfv[t] = *reinterpret_cast<const bf16x8*>(
                    Bs + (wc + t * 16 + fr) * 64 + (((kk * 4 + fq) ^ sw7) * 8));
#pragma unroll
            for (int mt = 0; mt < MT; ++mt)
#pragma unroll
                for (int nt = 0; nt < NT; ++nt)
                    acc[mt][nt] = __builtin_amdgcn_mfma_f32_16x16x32_bf16(af[mt], bfv[nt], acc[mt][nt], 0, 0, 0);
        }
    }

#pragma unroll
    for (int nt = 0; nt < NT; ++nt) {
        const int n = n0 + wc + nt * 16 + fr;
        const float bval = bias[n];
#pragma unroll
        for (int mt = 0; mt < MT; ++mt) {
#pragma unroll
            for (int r = 0; r < 4; ++r) {
                const int m = m0 + wr + mt * 16 + fq * 4 + r;
                const float val = (acc[mt][nt][r] + bval) * scale;
                if (MODE == 2) {
                    reinterpret_cast<float*>(out)[(size_t)m * D_MODEL + n] = val;
                } else {
                    const int b = m >> 11, s = m & (S_LEN - 1);
                    const int h = n >> 6, dk = n & 63;
                    const unsigned short o16 = f2bf(val);
                    if (MODE == 0)
                        reinterpret_cast<unsigned short*>(out)[(((size_t)(b * N_HEADS + h)) * S_LEN + s) * HEAD_DIM + dk] = o16;
                    else
                        reinterpret_cast<unsigned short*>(out)[(((size_t)(b * N_HEADS + h)) * HEAD_DIM + dk) * S_LEN + s] = o16;
                }
            }
        }
    }
}

// fused Q/K/V projection
struct QKVArgs {
    const unsigned short* A[3];
    const unsigned short* Bt[3];
    const float* bias[3];
    unsigned short* out[3];
};

// XCD-chunked swizzle: per z-slice, 256 tiles; XCD k (= linear id % 8) gets tiles
// k*32..k*32+31 = 4 m-panels x 8 n-panels -> per-XCD L2 working set 1 MB A + 2 MB B,
// each A panel fetched by exactly one XCD (was: every XCD, ~8x A over-fetch).
__global__ __launch_bounds__(256)
void qkv_gemm_kernel(QKVArgs args) {
    __shared__ __align__(16) unsigned short As[128 * 64];
    __shared__ __align__(16) unsigned short Bs[128 * 64];
    const int z  = blockIdx.z;
    const int wg = blockIdx.x + (blockIdx.y << 3);     // 0..255 linear within slice
    const int t  = ((wg & 7) << 5) + (wg >> 3);        // bijective (256 % 8 == 0)
    const int n0 = (t & 7) * 128;
    const int m0 = (t >> 3) * 128;
    // Q gets 0.125*log2(e) folded in so attention uses exp2 with no per-element scale
    if (z == 0)
        gemm_body<128, 128, 0>(args.A[0], args.Bt[0], args.bias[0], args.out[0], m0, n0, 0.18033688011112f, As, Bs);
    else if (z == 1)
        gemm_body<128, 128, 0>(args.A[1], args.Bt[1], args.bias[1], args.out[1], m0, n0, 1.0f, As, Bs);
    else
        gemm_body<128, 128, 1>(args.A[2], args.Bt[2], args.bias[2], args.out[2], m0, n0, 1.0f, As, Bs);
}

// O projection: 64x128 tiles -> 512 blocks, same XCD-chunked swizzle
// (XCD k gets 64 contiguous tiles = 8 m-panels x 8 n -> 1 MB A + 2 MB B per L2).
__global__ __launch_bounds__(256)
void oproj_gemm_kernel(const unsigned short* __restrict__ A,
                       const unsigned short* __restrict__ Bt,
                       const float* __restrict__ bias,
                       float* __restrict__ out) {
    __shared__ __align__(16) unsigned short As[64 * 64];
    __shared__ __align__(16) unsigned short Bs[128 * 64];
    const int wg = blockIdx.x + (blockIdx.y << 3);     // 0..511
    const int t  = ((wg & 7) << 6) + (wg >> 3);        // bijective (512 % 8 == 0)
    const int n0 = (t & 7) * 128;
    const int m0 = (t >> 3) * 64;
    gemm_body<64, 128, 2>(A, Bt, bias, out, m0, n0, 1.0f, As, Bs);
}

// ---------- attention (R0 verbatim — best measured: 70.9 us) ----------
// 128 threads (2 waves), 64 q rows/block, 32 q rows/wave (2 subtiles of 16).
// Grid 1024 blocks -> 4 blocks/CU (LDS 33 KB) = 4 independent barrier domains/CU,
// so one block's global_load_lds drain overlaps another's MFMA/VALU compute.
// S^T = K Q^T so per-lane acc is contiguous kv; P packs via pk_rne -> b64 write.
__global__ __launch_bounds__(128)
void attn_kernel(const unsigned short* __restrict__ qhp,
                 const unsigned short* __restrict__ khp,
                 const unsigned short* __restrict__ vtp,
                 unsigned short* __restrict__ outp) {
    __shared__ __align__(16) unsigned short Qs[64 * 64];
    __shared__ __align__(16) unsigned short Ks[64 * 64];
    __shared__ __align__(16) unsigned short Vs[64 * 64];
    __shared__ __align__(16) unsigned short Ps[2][32 * 72];  // per-wave [q_local][kv]

    const int tid  = threadIdx.x;
    const int wid  = tid >> 6;             // 0..1
    const int lane = tid & 63;
    const int b = blockIdx.z, h = blockIdx.y;
    const int q0 = blockIdx.x * 64;

    const unsigned short* qbase = qhp + (size_t)(b * N_HEADS + h) * S_LEN * HEAD_DIM;
    const unsigned short* kbase = khp + (size_t)(b * N_HEADS + h) * S_LEN * HEAD_DIM;
    const unsigned short* vbase = vtp + (size_t)(b * N_HEADS + h) * HEAD_DIM * S_LEN;

    const int srow = lane >> 3;            // 0..7
    const int gch  = (lane & 7) ^ srow;    // swizzled 16B chunk within 128B row
    const int fr = lane & 15;
    const int fq = lane >> 4;
    const int sw7 = fr & 7;

    // stage Q (64 rows = 8 chunks of 8 rows); wave wid takes chunks wid*4..wid*4+3
#pragma unroll
    for (int i = 0; i < 4; ++i) {
        const int c = wid * 4 + i;
        const int row = c * 8 + srow;
        gload_lds16(qbase + (size_t)(q0 + row) * HEAD_DIM + gch * 8, Qs + c * 512);
    }
    __syncthreads();

    // hoist Q B-operand fragments: subtile qh2 covers rows wid*32 + qh2*16 + fr
    bf16x8 qf[2][2];
#pragma unroll
    for (int qh2 = 0; qh2 < 2; ++qh2)
#pragma unroll
        for (int kk = 0; kk < 2; ++kk)
            qf[qh2][kk] = *reinterpret_cast<const bf16x8*>(
                Qs + (wid * 32 + qh2 * 16 + fr) * 64 + (((kk * 4 + fq) ^ sw7) * 8));

    floatx4 o_acc[2][4];
#pragma unroll
    for (int i = 0; i < 2; ++i)
#pragma unroll
        for (int j = 0; j < 4; ++j) o_acc[i][j] = (floatx4)0.0f;
    float l_sum[2] = {0.0f, 0.0f};

    for (int kv0 = 0; kv0 < S_LEN; kv0 += 64) {
        if (kv0) __syncthreads();
#pragma unroll
        for (int i = 0; i < 4; ++i) {
            const int c = wid * 4 + i;
            const int row = c * 8 + srow;
            gload_lds16(kbase + (size_t)(kv0 + row) * HEAD_DIM + gch * 8, Ks + c * 512);
            gload_lds16(vbase + (size_t)row * S_LEN + kv0 + gch * 8,       Vs + c * 512);
        }
        __syncthreads();

        // S^T[kv][q]: A = K rows (shared across q subtiles), B = Q rows
        floatx4 st[2][4];
#pragma unroll
        for (int i = 0; i < 2; ++i)
#pragma unroll
            for (int j = 0; j < 4; ++j) st[i][j] = (floatx4)0.0f;
#pragma unroll
        for (int nt = 0; nt < 4; ++nt) {
#pragma unroll
            for (int kk = 0; kk < 2; ++kk) {
                bf16x8 kf = *reinterpret_cast<const bf16x8*>(
                    Ks + (nt * 16 + fr) * 64 + (((kk * 4 + fq) ^ sw7) * 8));
                st[0][nt] = __builtin_amdgcn_mfma_f32_16x16x32_bf16(kf, qf[0][kk], st[0][nt], 0, 0, 0);
                st[1][nt] = __builtin_amdgcn_mfma_f32_16x16x32_bf16(kf, qf[1][kk], st[1][nt], 0, 0, 0);
            }
        }

        // P = exp2(S^T) (scale pre-folded into Q); lane holds P[q=fr][kv=nt*16+fq*4+r]
#pragma unroll
        for (int qh2 = 0; qh2 < 2; ++qh2) {
#pragma unroll
            for (int nt = 0; nt < 4; ++nt) {
                float p0 = __builtin_amdgcn_exp2f(st[qh2][nt][0]);
                float p1 = __builtin_amdgcn_exp2f(st[qh2][nt][1]);
                float p2 = __builtin_amdgcn_exp2f(st[qh2][nt][2]);
                float p3 = __builtin_amdgcn_exp2f(st[qh2][nt][3]);
                l_sum[qh2] += (p0 + p1) + (p2 + p3);
                uint2 w;
                w.x = pk_rne(p0, p1);
                w.y = pk_rne(p2, p3);
                *reinterpret_cast<uint2*>(Ps[wid] + (qh2 * 16 + fr) * 72 + nt * 16 + fq * 4) = w;
            }
        }
        __asm__ volatile("s_waitcnt lgkmcnt(0)" ::: "memory");  // wave-local write->read fence

        // O += P V   (Vs = V^T rows [d][kv]; V fragments shared across q subtiles)
#pragma unroll
        for (int kk = 0; kk < 2; ++kk) {
            bf16x8 pf0 = *reinterpret_cast<const bf16x8*>(Ps[wid] + (fr)      * 72 + kk * 32 + fq * 8);
            bf16x8 pf1 = *reinterpret_cast<const bf16x8*>(Ps[wid] + (16 + fr) * 72 + kk * 32 + fq * 8);
#pragma unroll
            for (int dt = 0; dt < 4; ++dt) {
                bf16x8 vf = *reinterpret_cast<const bf16x8*>(
                    Vs + (dt * 16 + fr) * 64 + (((kk * 4 + fq) ^ sw7) * 8));
                o_acc[0][dt] = __builtin_amdgcn_mfma_f32_16x16x32_bf16(pf0, vf, o_acc[0][dt], 0, 0, 0);
                o_acc[1][dt] = __builtin_amdgcn_mfma_f32_16x16x32_bf16(pf1, vf, o_acc[1][dt], 0, 0, 0);
            }
        }
    }

#pragma unroll
    for (int qh2 = 0; qh2 < 2; ++qh2) {
        float l = l_sum[qh2];
        l += __shfl_xor(l, 16);
        l += __shfl_xor(l, 32);
        float linv[4];
#pragma unroll
        for (int r = 0; r < 4; ++r)
            linv[r] = __builtin_amdgcn_rcpf(__shfl(l, fq * 4 + r));
#pragma unroll
        for (int dt = 0; dt < 4; ++dt) {
#pragma unroll
            for (int r = 0; r < 4; ++r) {
                const int s  = q0 + wid * 32 + qh2 * 16 + fq * 4 + r;
                const int dk = dt * 16 + fr;
                const float val = o_acc[qh2][dt][r] * linv[r];
                outp[((size_t)(b * S_LEN + s)) * D_MODEL + h * HEAD_DIM + dk] = f2bf(val);
            }
        }
    }
}

extern "C" void kernel_launch(void* const* d_in, const int* in_sizes, int n_in,
                              void* d_out, int out_size, void* d_ws, size_t ws_size,
                              hipStream_t stream) {
    (void)in_sizes; (void)n_in; (void)out_size; (void)ws_size;
    const float* q  = (const float*)d_in[0];
    const float* k  = (const float*)d_in[1];
    const float* v  = (const float*)d_in[2];
    // d_in[3] = mask: mathematical no-op in the reference
    const float* Wq = (const float*)d_in[4];
    const float* bq = (const float*)d_in[5];
    const float* Wk = (const float*)d_in[6];
    const float* bk = (const float*)d_in[7];
    const float* Wv = (const float*)d_in[8];
    const float* bv = (const float*)d_in[9];
    const float* Wo = (const float*)d_in[10];
    const float* bo = (const float*)d_in[11];
    float* out = (float*)d_out;

    char* ws = (char*)d_ws;
    const size_t SZ_ACT = (size_t)BATCH * S_LEN * D_MODEL * 2;  // 8 MB
    const size_t SZ_W   = (size_t)D_MODEL * D_MODEL * 2;        // 2 MB
    unsigned short* qb   = (unsigned short*)(ws);
    unsigned short* kb   = (unsigned short*)(ws + SZ_ACT);
    unsigned short* vb   = (unsigned short*)(ws + 2 * SZ_ACT);
    unsigned short* Wqt  = (unsigned short*)(ws + 3 * SZ_ACT);
    unsigned short* Wkt  = (unsigned short*)(ws + 3 * SZ_ACT + SZ_W);
    unsigned short* Wvt  = (unsigned short*)(ws + 3 * SZ_ACT + 2 * SZ_W);
    unsigned short* Wot  = (unsigned short*)(ws + 3 * SZ_ACT + 3 * SZ_W);
    unsigned short* qhb  = (unsigned short*)(ws + 3 * SZ_ACT + 4 * SZ_W);
    unsigned short* khb  = (unsigned short*)(ws + 4 * SZ_ACT + 4 * SZ_W);
    unsigned short* vtb  = (unsigned short*)(ws + 5 * SZ_ACT + 4 * SZ_W);
    unsigned short* attn = qb;  // qb dead after Q projection

    PrepArgs pargs;
    pargs.src[0] = q;  pargs.src[1] = k;  pargs.src[2] = v;
    pargs.dst[0] = qb; pargs.dst[1] = kb; pargs.dst[2] = vb;
    pargs.W[0] = Wq;  pargs.W[1] = Wk;  pargs.W[2] = Wv;  pargs.W[3] = Wo;
    pargs.Wt[0] = Wqt; pargs.Wt[1] = Wkt; pargs.Wt[2] = Wvt; pargs.Wt[3] = Wot;
    prep_kernel<<<dim3(CONV_BLOCKS + 1024), 256, 0, stream>>>(pargs);

    QKVArgs gargs;
    gargs.A[0] = qb;  gargs.A[1] = kb;  gargs.A[2] = vb;
    gargs.Bt[0] = Wqt; gargs.Bt[1] = Wkt; gargs.Bt[2] = Wvt;
    gargs.bias[0] = bq; gargs.bias[1] = bk; gargs.bias[2] = bv;
    gargs.out[0] = qhb; gargs.out[1] = khb; gargs.out[2] = vtb;
    qkv_gemm_kernel<<<dim3(8, 32, 3), 256, 0, stream>>>(gargs);

    attn_kernel<<<dim3(S_LEN / 64, N_HEADS, BATCH), 128, 0, stream>>>(qhb, khb, vtb, attn);

    oproj_gemm_kernel<<<dim3(8, 64), 256, 0, stream>>>(attn, Wot, bo, out);
}